// Round 1
// 89.935 us; speedup vs baseline: 1.0794x; 1.0794x over previous
//
#include <hip/hip_runtime.h>
#include <math.h>

#define Bn 4
#define Hn 512
#define Wn 229
#define Cn 32
#define OUTn 88
#define BH (Bn*Hn)            // 2048
#define FP_SIZE (BH*OUTn)     // 180224
#define CW (Cn*Wn)            // 7328
#define KK 9                  // 3x3 window
#define ATT_ROW (Wn*KK)       // 2061 floats per bh row

// workspace layout (float offsets)
#define WS_SCAL 0             // 8 floats: A, Rt[0..2], Rf[0..2], 0
#define WS_WEFF 16            // OUTn*Wn = 20152 floats, layout [w][o]  (TRANSPOSED)

// ---------------- kernel 1: collapsed scalars + effective head matrix ----------------
// WeffT[w][o] = sum_c W_lin[o*CW + c*Wn + w] * Wv[c]
// tid = o*Wn + w: consecutive lanes -> consecutive w -> W_lin reads coalesced.
// Writes to [w][o] are scattered, but prep touches only 80 KB once (not hot).
__global__ __launch_bounds__(256) void prep_kernel(
    const float* __restrict__ Wq, const float* __restrict__ Wk,
    const float* __restrict__ Wv, const float* __restrict__ rel_t,
    const float* __restrict__ rel_f, const float* __restrict__ W_lin,
    float* __restrict__ ws) {
  __shared__ float wv[Cn];
  if (threadIdx.x < Cn) wv[threadIdx.x] = Wv[threadIdx.x];
  __syncthreads();
  const int tid = blockIdx.x * 256 + threadIdx.x;

  if (tid < 8) {  // block 0 lanes 0..7: the 7 collapsed scalars (+ zero pad)
    float acc = 0.f;
    if (tid == 0) {
      #pragma unroll
      for (int c = 0; c < Cn; ++c) acc += Wq[c] * Wk[c];
    } else if (tid < 4) {
      const int i = tid - 1;
      #pragma unroll
      for (int c = 0; c < 16; ++c) acc += Wq[c] * rel_t[c*3 + i];
    } else if (tid < 7) {
      const int j = tid - 4;
      #pragma unroll
      for (int c = 0; c < 16; ++c) acc += Wq[16 + c] * rel_f[c*3 + j];
    }
    ws[WS_SCAL + tid] = acc;
  }

  if (tid < OUTn * Wn) {
    const int o = tid / Wn;
    const int w = tid - o * Wn;
    const float* src = W_lin + o * CW + w;
    float acc = 0.f;
    #pragma unroll
    for (int c = 0; c < Cn; ++c) acc = fmaf(src[c * Wn], wv[c], acc);
    ws[WS_WEFF + w * OUTn + o] = acc;   // transposed [w][o]
  }
}

// ---------------- kernel 2: fused attention + head, one block per bh row ----------------
__global__ __launch_bounds__(256) void main_kernel(
    const float* __restrict__ spec, const float* __restrict__ ws,
    const float* __restrict__ b_lin, float* __restrict__ out) {
  __shared__ float srow[3][260];   // 3 spec rows, +1 shift, zero-padded halo
  __shared__ float satt[ATT_ROW + 3];
  __shared__ float sx[232];        // o[w] for this row
  __shared__ float scal[8];
  __shared__ float spart[2 * OUTn];

  const int bh = blockIdx.x;       // 0..2047
  const int h  = bh & (Hn - 1);
  const int t  = threadIdx.x;

  if (t < 8) scal[t] = ws[WS_SCAL + t];

  // stage rows h-1, h, h+1 (of the same batch; bh+-1 stays in-batch iff h valid)
  #pragma unroll
  for (int r = 0; r < 3; ++r) {
    const int hh = h + r - 1;
    const bool hin = (unsigned)hh < (unsigned)Hn;
    float v = 0.f;
    if (hin && t < Wn) v = spec[(size_t)(bh + r - 1) * Wn + t];
    srow[r][t + 1] = v;            // t up to 255 -> index up to 256 < 260
    if (t == 255) srow[r][0] = 0.f;
  }
  __syncthreads();

  // per-position attention (threads 0..228)
  if (t < Wn) {
    const int w = t;
    const float A = scal[0];
    const float s = srow[1][w + 1];
    float e[KK], v[KK];
    float m = -1e30f;
    #pragma unroll
    for (int i = 0; i < 3; ++i) {
      const float rt = scal[1 + i];
      #pragma unroll
      for (int j = 0; j < 3; ++j) {
        const int k = i*3 + j;
        const float val = srow[i][w + j];
        v[k] = val;
        const float ek = s * (fmaf(A, val, rt) + scal[4 + j]);
        e[k] = ek;
        m = fmaxf(m, ek);
      }
    }
    float sum = 0.f;
    #pragma unroll
    for (int k = 0; k < KK; ++k) { e[k] = __expf(e[k] - m); sum += e[k]; }
    const float inv = 1.f / sum;
    float o = 0.f;
    #pragma unroll
    for (int k = 0; k < KK; ++k) {
      const float a = e[k] * inv;
      satt[w * KK + k] = a;
      o = fmaf(a, v[k], o);
    }
    sx[w] = o;
  }
  __syncthreads();

  // coalesced attn write: 2061 floats at out[FP_SIZE + bh*2061]
  // stores are fire-and-forget; issue them before the head loop
  {
    float* abase = out + FP_SIZE + (size_t)bh * ATT_ROW;
    #pragma unroll
    for (int p = t; p < ATT_ROW; p += 256) abase[p] = satt[p];
  }

  // head: frame_pred[bh][o] = sigmoid(b[o] + sum_w WeffT[w][o]*sx[w])
  // split the 229-long dot into two halves on two thread groups:
  //   t in [0,88)      -> o = t,      w in [0,115)
  //   t in [128,216)   -> o = t-128,  w in [115,229)
  // WeffT[w*88+o]: lanes o consecutive -> fully coalesced (L2-hot, 80 KB total)
  {
    int o = -1, w0 = 0, w1 = 0;
    if (t < OUTn)                         { o = t;       w0 = 0;   w1 = 115; }
    else if (t >= 128 && t < 128 + OUTn)  { o = t - 128; w0 = 115; w1 = Wn;  }
    if (o >= 0) {
      const float* wt = ws + WS_WEFF + o;
      float acc = 0.f;
      #pragma unroll 8
      for (int w = w0; w < w1; ++w) acc = fmaf(wt[(size_t)w * OUTn], sx[w], acc);
      spart[(t >> 7) * OUTn + o] = acc;
    }
  }
  __syncthreads();

  if (t < OUTn) {
    const float acc = b_lin[t] + spart[t] + spart[OUTn + t];
    out[(size_t)bh * OUTn + t] = 1.f / (1.f + __expf(-acc));
  }
}

extern "C" void kernel_launch(void* const* d_in, const int* in_sizes, int n_in,
                              void* d_out, int out_size, void* d_ws, size_t ws_size,
                              hipStream_t stream) {
  const float* spec  = (const float*)d_in[0];
  const float* Wq    = (const float*)d_in[1];
  const float* Wk    = (const float*)d_in[2];
  const float* Wv    = (const float*)d_in[3];
  const float* rel_t = (const float*)d_in[4];
  const float* rel_f = (const float*)d_in[5];
  const float* W_lin = (const float*)d_in[6];
  const float* b_lin = (const float*)d_in[7];
  float* out = (float*)d_out;
  float* ws  = (float*)d_ws;

  prep_kernel<<<(OUTn*Wn + 255)/256, 256, 0, stream>>>(Wq, Wk, Wv, rel_t, rel_f, W_lin, ws);
  main_kernel<<<BH, 256, 0, stream>>>(spec, ws, b_lin, out);
}